// Round 1
// baseline (328.882 us; speedup 1.0000x reference)
//
#include <hip/hip_runtime.h>
#include <hip/hip_bf16.h>

#define TPB 256
#define NCODES 1024
#define DIMS 256
#define PIXB 64
#define XPAD 264      // xs row stride (ushorts): 528 B, 16B-aligned
#define DELTA 3.0f    // screening margin (bf16 worst-case dot error ~1.3; 3.0 is safe)
#define CAP 16        // candidate capacity per pixel (overflow -> full rescan)

typedef __attribute__((ext_vector_type(8))) short bf16x8;
typedef __attribute__((ext_vector_type(4))) float f32x4;

// prep: eb[c][d] = bf16(emb[c][d]);  e2[c] = sum_d emb[c][d]^2 (exact fp32)
__global__ __launch_bounds__(64) void prep_kernel(const float* __restrict__ emb,
                                                  ushort* __restrict__ eb,
                                                  float* __restrict__ e2) {
    const int c = blockIdx.x;
    const int l = threadIdx.x;           // 64 lanes, 4 dims each
    float4 v = *(const float4*)(emb + (size_t)c * DIMS + 4 * l);
    __hip_bfloat16 h0 = __float2bfloat16(v.x), h1 = __float2bfloat16(v.y);
    __hip_bfloat16 h2 = __float2bfloat16(v.z), h3 = __float2bfloat16(v.w);
    ushort4 u;
    u.x = *(ushort*)&h0; u.y = *(ushort*)&h1; u.z = *(ushort*)&h2; u.w = *(ushort*)&h3;
    *(ushort4*)(eb + (size_t)c * DIMS + 4 * l) = u;
    float s = v.x * v.x + v.y * v.y + v.z * v.z + v.w * v.w;
#pragma unroll
    for (int off = 1; off < 64; off <<= 1) s += __shfl_xor(s, off);
    if (l == 0) e2[c] = s;
}

__global__ __launch_bounds__(TPB, 3) void vq_kernel(const float* __restrict__ z,
                                                    const float* __restrict__ emb,
                                                    const ushort* __restrict__ eb,
                                                    const float* __restrict__ e2g,
                                                    int* __restrict__ out) {
    __shared__ __align__(16) ushort xs[PIXB * XPAD];   // 33792 B: bf16 x, [px][dim]
    __shared__ float wmin[4 * 64];                     // per-wave chunk min per px
    __shared__ float minval[64];                       // global running min per px
    __shared__ int   cnt[64];
    __shared__ int   cand[64 * CAP];

    const int tid = threadIdx.x;
    const int w   = tid >> 6;     // wave 0..3
    const int L   = tid & 63;     // lane
    const int col = L & 15;       // MFMA col (= pixel within n-tile)
    const int q   = L >> 4;       // MFMA quad
    const int pixbase = blockIdx.x * PIXB;
    const int t  = pixbase >> 12;
    const int n0 = pixbase & 4095;

    // ---- phase 1: stage x (fp32 global -> bf16 LDS), wave w does dims w*64..+63 ----
    {
        const float* zp = z + (((size_t)t * DIMS + w * 64) << 12) + n0 + L;
#pragma unroll 8
        for (int i = 0; i < 64; ++i) {
            float v = zp[(size_t)i << 12];
            __hip_bfloat16 h = __float2bfloat16(v);
            xs[L * XPAD + w * 64 + i] = *(ushort*)&h;
        }
    }
    if (tid < 64) { minval[tid] = 3.4e38f; cnt[tid] = 0; }
    __syncthreads();

    // per-lane E pointer: code row (w*64 + col), dim q*8, chunk 0
    const ushort* ebp = eb + (size_t)(w * 64 + col) * DIMS + q * 8;

    // ---- phase 2: barrier-free MFMA screening, 4 chunks of 256 codes ----
#pragma unroll 1
    for (int cc = 0; cc < 4; ++cc) {
        const ushort* ebc = ebp + ((size_t)cc << 16);   // cc*256*DIMS

        f32x4 acc[4][4];
#pragma unroll
        for (int mt = 0; mt < 4; ++mt)
#pragma unroll
            for (int nt = 0; nt < 4; ++nt) acc[mt][nt] = (f32x4){0.f, 0.f, 0.f, 0.f};

        // prime pipeline: fragments for kc=0
        bf16x8 af[4], bfr[4];
#pragma unroll
        for (int mt = 0; mt < 4; ++mt)
            af[mt] = *(const bf16x8*)(ebc + mt * 16 * DIMS);
#pragma unroll
        for (int nt = 0; nt < 4; ++nt)
            bfr[nt] = *(const bf16x8*)&xs[(nt * 16 + col) * XPAD + q * 8];

#pragma unroll
        for (int kc = 0; kc < 8; ++kc) {
            bf16x8 afn[4], bfn[4];
            if (kc < 7) {   // prefetch next K-step while MFMAs run
#pragma unroll
                for (int mt = 0; mt < 4; ++mt)
                    afn[mt] = *(const bf16x8*)(ebc + mt * 16 * DIMS + (kc + 1) * 32);
#pragma unroll
                for (int nt = 0; nt < 4; ++nt)
                    bfn[nt] = *(const bf16x8*)&xs[(nt * 16 + col) * XPAD + (kc + 1) * 32 + q * 8];
            }
#pragma unroll
            for (int mt = 0; mt < 4; ++mt)
#pragma unroll
                for (int nt = 0; nt < 4; ++nt)
                    acc[mt][nt] = __builtin_amdgcn_mfma_f32_16x16x32_bf16(
                        af[mt], bfr[nt], acc[mt][nt], 0, 0, 0);
            if (kc < 7) {
#pragma unroll
                for (int i = 0; i < 4; ++i) { af[i] = afn[i]; bfr[i] = bfn[i]; }
            }
        }

        // epilogue: s = e2[c] - 2*dot ; C layout: col=lane&15 (px), row=q*4+r (code)
        f32x4 e4[4];
#pragma unroll
        for (int mt = 0; mt < 4; ++mt)
            e4[mt] = *(const f32x4*)(e2g + cc * 256 + w * 64 + mt * 16 + q * 4);

        // 1) per-(wave,px) chunk min
#pragma unroll
        for (int nt = 0; nt < 4; ++nt) {
            float m = 3.4e38f;
#pragma unroll
            for (int mt = 0; mt < 4; ++mt)
#pragma unroll
                for (int r = 0; r < 4; ++r) {
                    float s = e4[mt][r] - 2.f * acc[mt][nt][r];
                    m = fminf(m, s);
                }
            m = fminf(m, __shfl_xor(m, 16));
            m = fminf(m, __shfl_xor(m, 32));
            wmin[w * 64 + nt * 16 + col] = m;    // all q-copies write same value
        }
        __syncthreads();
        if (tid < 64) {
            float m = minval[tid];
#pragma unroll
            for (int ww = 0; ww < 4; ++ww) m = fminf(m, wmin[ww * 64 + tid]);
            minval[tid] = m;
        }
        __syncthreads();
        // 2) candidate scan (running-min threshold => superset of final candidate set)
#pragma unroll
        for (int nt = 0; nt < 4; ++nt) {
            const int px = nt * 16 + col;
            const float thr = minval[px] + DELTA;
#pragma unroll
            for (int mt = 0; mt < 4; ++mt)
#pragma unroll
                for (int r = 0; r < 4; ++r) {
                    float s = e4[mt][r] - 2.f * acc[mt][nt][r];
                    if (s <= thr) {
                        int pos = atomicAdd(&cnt[px], 1);
                        if (pos < CAP)
                            cand[px * CAP + pos] = cc * 256 + w * 64 + mt * 16 + q * 4 + r;
                    }
                }
        }
    }
    __syncthreads();

    // ---- phase 3: exact fp32 rescore of candidates; wave w does px w*16..+15 ----
#pragma unroll 1
    for (int pi = 0; pi < 16; ++pi) {
        const int px = w * 16 + pi;
        const int n  = cnt[px];
        if (n == 1) {
            // singleton candidate set: the true argmin is guaranteed to be a
            // candidate, so it IS the answer — skip the exact rescore entirely.
            if (L == 0) out[pixbase + px] = cand[px * CAP];
            continue;
        }
        // lane L holds dims 4L..4L+3 of x (exact fp32 from pristine z)
        const float* zp = z + (((size_t)t * DIMS + 4 * L) << 12) + n0 + px;
        float x0 = zp[0];
        float x1 = zp[(size_t)1 << 12];
        float x2 = zp[(size_t)2 << 12];
        float x3 = zp[(size_t)3 << 12];
        float bs = 3.4e38f;
        int   bi = 0;
        if (n <= CAP) {
            for (int k = 0; k < n; ++k) {
                int c = cand[px * CAP + k];
                float4 ev = *(const float4*)(emb + (size_t)c * DIMS + 4 * L);
                float p = x0 * ev.x + x1 * ev.y + x2 * ev.z + x3 * ev.w;
#pragma unroll
                for (int off = 1; off < 64; off <<= 1) p += __shfl_xor(p, off);
                float s = e2g[c] - 2.f * p;
                if (s < bs || (s == bs && c < bi)) { bs = s; bi = c; }
            }
        } else {
            // overflow fallback (expected never): exact scan of all codes
            for (int c = 0; c < NCODES; ++c) {
                float4 ev = *(const float4*)(emb + (size_t)c * DIMS + 4 * L);
                float p = x0 * ev.x + x1 * ev.y + x2 * ev.z + x3 * ev.w;
#pragma unroll
                for (int off = 1; off < 64; off <<= 1) p += __shfl_xor(p, off);
                float s = e2g[c] - 2.f * p;
                if (s < bs || (s == bs && c < bi)) { bs = s; bi = c; }
            }
        }
        if (L == 0) out[pixbase + px] = bi;
    }
}

extern "C" void kernel_launch(void* const* d_in, const int* in_sizes, int n_in,
                              void* d_out, int out_size, void* d_ws, size_t ws_size,
                              hipStream_t stream) {
    const float* z   = (const float*)d_in[0];   // (16,256,64,64) fp32
    const float* emb = (const float*)d_in[1];   // (1024,256) fp32
    int* out = (int*)d_out;                     // (16,64,64) int32

    ushort* eb = (ushort*)d_ws;                          // 1024*256 bf16 = 512 KB
    float*  e2 = (float*)((char*)d_ws + (size_t)NCODES * DIMS * sizeof(ushort)); // 4 KB

    prep_kernel<<<NCODES, 64, 0, stream>>>(emb, eb, e2);
    vq_kernel<<<(16 * 64 * 64) / PIXB, TPB, 0, stream>>>(z, emb, eb, e2, out);
}

// Round 2
// 263.429 us; speedup vs baseline: 1.2485x; 1.2485x over previous
//
#include <hip/hip_runtime.h>
#include <hip/hip_bf16.h>

#define TPB 256
#define NCODES 1024
#define DIMS 256
#define PIXB 64
#define XPAD 264      // xs row stride (ushorts): 528 B, 16B-aligned, 2-way banks on b128 reads
#define DELTA 3.0f    // screening margin (bf16 worst-case dot error ~1.3; 3.0 is safe)
#define CAP 16        // candidate capacity per pixel (overflow -> full rescan)

typedef __attribute__((ext_vector_type(8))) short bf16x8;
typedef __attribute__((ext_vector_type(4))) float f32x4;

__device__ __forceinline__ void gll16(const void* g, void* l) {
    // async global->LDS, 16 B per lane; LDS dest = wave-uniform base + lane*16
    __builtin_amdgcn_global_load_lds(
        (const __attribute__((address_space(1))) void*)g,
        (__attribute__((address_space(3))) void*)l, 16, 0, 0);
}

// prep: eb[c][d] = bf16(emb[c][d]);  e2[c] = sum_d emb[c][d]^2 (exact fp32)
__global__ __launch_bounds__(64) void prep_kernel(const float* __restrict__ emb,
                                                  ushort* __restrict__ eb,
                                                  float* __restrict__ e2) {
    const int c = blockIdx.x;
    const int l = threadIdx.x;           // 64 lanes, 4 dims each
    float4 v = *(const float4*)(emb + (size_t)c * DIMS + 4 * l);
    __hip_bfloat16 h0 = __float2bfloat16(v.x), h1 = __float2bfloat16(v.y);
    __hip_bfloat16 h2 = __float2bfloat16(v.z), h3 = __float2bfloat16(v.w);
    ushort4 u;
    u.x = *(ushort*)&h0; u.y = *(ushort*)&h1; u.z = *(ushort*)&h2; u.w = *(ushort*)&h3;
    *(ushort4*)(eb + (size_t)c * DIMS + 4 * l) = u;
    float s = v.x * v.x + v.y * v.y + v.z * v.z + v.w * v.w;
#pragma unroll
    for (int off = 1; off < 64; off <<= 1) s += __shfl_xor(s, off);
    if (l == 0) e2[c] = s;
}

__global__ __launch_bounds__(TPB, 2) void vq_kernel(const float* __restrict__ z,
                                                    const float* __restrict__ emb,
                                                    const ushort* __restrict__ eb,
                                                    const float* __restrict__ e2g,
                                                    int* __restrict__ out) {
    __shared__ __align__(16) ushort xs[PIXB * XPAD];   // 33792 B: bf16 x, [px][dim]
    // es: double-buffered, WAVE-PRIVATE E tiles. Layout per (buf,wave): 4 KB region,
    // dq-major: [dq(0..3)][code(0..63)][8 dims] -> plane 1 KB, granule 16 B.
    // ds_read_b128 of af: addr = q*1024 + code*16 -> bank col*4 mod 32 -> 2-way (free).
    __shared__ __align__(16) ushort es[2 * 4 * 2048];  // 32768 B
    __shared__ float wmin[4 * 64];                     // per-wave chunk min per px
    __shared__ float minval[64];                       // global running min per px
    __shared__ int   cnt[64];
    __shared__ int   cand[64 * CAP];

    const int tid = threadIdx.x;
    const int w   = tid >> 6;     // wave 0..3
    const int L   = tid & 63;     // lane
    const int col = L & 15;       // MFMA col (= pixel within n-tile)
    const int q   = L >> 4;       // MFMA quad
    const int pixbase = blockIdx.x * PIXB;
    const int t  = pixbase >> 12;
    const int n0 = pixbase & 4095;

    // STAGE: wave w stages its own 64 code rows (codes w*64..+63), 32 dims of step kc,
    // chunk cc, into buffer b. 4 x gll16: plane j holds dims kc*32 + j*8 for all codes.
    // Wave-local: NO barrier needed; sync via vmcnt only.
#define STAGE(b, cc_, kc_) do {                                                   \
        const ushort* _src = eb + ((size_t)(((cc_) << 8) + (w << 6) + L) << 8)    \
                                + ((kc_) << 5);                                   \
        ushort* _dst = &es[(((b) << 2) + w) * 2048];                              \
        gll16(_src,      _dst);                                                   \
        gll16(_src + 8,  _dst + 512);                                             \
        gll16(_src + 16, _dst + 1024);                                            \
        gll16(_src + 24, _dst + 1536);                                            \
    } while (0)

    // ---- phase 1: stage x (fp32 global -> bf16 LDS), wave w does dims w*64..+63 ----
    // z is single-use streaming data: nontemporal so it doesn't evict eb from L2.
    {
        const float* zp = z + (((size_t)t * DIMS + w * 64) << 12) + n0 + L;
#pragma unroll 8
        for (int i = 0; i < 64; ++i) {
            float v = __builtin_nontemporal_load(zp + ((size_t)i << 12));
            __hip_bfloat16 h = __float2bfloat16(v);
            xs[L * XPAD + w * 64 + i] = *(ushort*)&h;
        }
    }
    if (tid < 64) { minval[tid] = 3.4e38f; cnt[tid] = 0; }

    STAGE(0, 0, 0);        // prologue: tile for step 0 (drained by the barrier below)
    __syncthreads();       // xs ready; prologue tile landed

    // ---- phase 2: barrier-free pipelined MFMA screening, 4 chunks of 256 codes ----
#pragma unroll 1
    for (int cc = 0; cc < 4; ++cc) {
        f32x4 acc[4][4];
#pragma unroll
        for (int mt = 0; mt < 4; ++mt)
#pragma unroll
            for (int nt = 0; nt < 4; ++nt) acc[mt][nt] = (f32x4){0.f, 0.f, 0.f, 0.f};

#pragma unroll
        for (int kc = 0; kc < 8; ++kc) {
            const int s = cc * 8 + kc;
            const int b = s & 1;
            if (s < 31) {                       // issue next tile into other buffer
                const int s1 = s + 1;
                STAGE(b ^ 1, s1 >> 3, s1 & 7);
                // 8 outstanding; wait until only the 4 newest remain -> tile s ready
                asm volatile("s_waitcnt vmcnt(4)" ::: "memory");
            } else {
                asm volatile("s_waitcnt vmcnt(0)" ::: "memory");
            }

            bf16x8 af[4], bfr[4];
            const ushort* ws = &es[((b << 2) + w) * 2048 + q * 512];
#pragma unroll
            for (int mt = 0; mt < 4; ++mt)
                af[mt] = *(const bf16x8*)(ws + (mt * 16 + col) * 8);
#pragma unroll
            for (int nt = 0; nt < 4; ++nt)
                bfr[nt] = *(const bf16x8*)&xs[(nt * 16 + col) * XPAD + kc * 32 + q * 8];
#pragma unroll
            for (int mt = 0; mt < 4; ++mt)
#pragma unroll
                for (int nt = 0; nt < 4; ++nt)
                    acc[mt][nt] = __builtin_amdgcn_mfma_f32_16x16x32_bf16(
                        af[mt], bfr[nt], acc[mt][nt], 0, 0, 0);
        }

        // epilogue: s = e2[c] - 2*dot ; C layout: col=lane&15 (px), row=q*4+r (code)
        f32x4 e4[4];
#pragma unroll
        for (int mt = 0; mt < 4; ++mt)
            e4[mt] = *(const f32x4*)(e2g + cc * 256 + w * 64 + mt * 16 + q * 4);

        // 1) per-(wave,px) chunk min
#pragma unroll
        for (int nt = 0; nt < 4; ++nt) {
            float m = 3.4e38f;
#pragma unroll
            for (int mt = 0; mt < 4; ++mt)
#pragma unroll
                for (int r = 0; r < 4; ++r) {
                    float s = e4[mt][r] - 2.f * acc[mt][nt][r];
                    m = fminf(m, s);
                }
            m = fminf(m, __shfl_xor(m, 16));
            m = fminf(m, __shfl_xor(m, 32));
            wmin[w * 64 + nt * 16 + col] = m;    // all q-copies write same value
        }
        __syncthreads();
        if (tid < 64) {
            float m = minval[tid];
#pragma unroll
            for (int ww = 0; ww < 4; ++ww) m = fminf(m, wmin[ww * 64 + tid]);
            minval[tid] = m;
        }
        __syncthreads();
        // 2) candidate scan (running-min threshold => superset of final candidate set)
#pragma unroll
        for (int nt = 0; nt < 4; ++nt) {
            const int px = nt * 16 + col;
            const float thr = minval[px] + DELTA;
#pragma unroll
            for (int mt = 0; mt < 4; ++mt)
#pragma unroll
                for (int r = 0; r < 4; ++r) {
                    float s = e4[mt][r] - 2.f * acc[mt][nt][r];
                    if (s <= thr) {
                        int pos = atomicAdd(&cnt[px], 1);
                        if (pos < CAP)
                            cand[px * CAP + pos] = cc * 256 + w * 64 + mt * 16 + q * 4 + r;
                    }
                }
        }
    }
    __syncthreads();

    // ---- phase 3: exact fp32 rescore of candidates; wave w does px w*16..+15 ----
#pragma unroll 1
    for (int pi = 0; pi < 16; ++pi) {
        const int px = w * 16 + pi;
        const int n  = cnt[px];
        if (n == 1) {
            // singleton candidate set: the true argmin is guaranteed to be a
            // candidate, so it IS the answer — skip the exact rescore entirely.
            if (L == 0) out[pixbase + px] = cand[px * CAP];
            continue;
        }
        // lane L holds dims 4L..4L+3 of x (exact fp32 from pristine z)
        const float* zp = z + (((size_t)t * DIMS + 4 * L) << 12) + n0 + px;
        float x0 = zp[0];
        float x1 = zp[(size_t)1 << 12];
        float x2 = zp[(size_t)2 << 12];
        float x3 = zp[(size_t)3 << 12];
        float bs = 3.4e38f;
        int   bi = 0;
        if (n <= CAP) {
            for (int k = 0; k < n; ++k) {
                int c = cand[px * CAP + k];
                float4 ev = *(const float4*)(emb + (size_t)c * DIMS + 4 * L);
                float p = x0 * ev.x + x1 * ev.y + x2 * ev.z + x3 * ev.w;
#pragma unroll
                for (int off = 1; off < 64; off <<= 1) p += __shfl_xor(p, off);
                float s = e2g[c] - 2.f * p;
                if (s < bs || (s == bs && c < bi)) { bs = s; bi = c; }
            }
        } else {
            // overflow fallback (expected never): exact scan of all codes
            for (int c = 0; c < NCODES; ++c) {
                float4 ev = *(const float4*)(emb + (size_t)c * DIMS + 4 * L);
                float p = x0 * ev.x + x1 * ev.y + x2 * ev.z + x3 * ev.w;
#pragma unroll
                for (int off = 1; off < 64; off <<= 1) p += __shfl_xor(p, off);
                float s = e2g[c] - 2.f * p;
                if (s < bs || (s == bs && c < bi)) { bs = s; bi = c; }
            }
        }
        if (L == 0) out[pixbase + px] = bi;
    }
#undef STAGE
}

extern "C" void kernel_launch(void* const* d_in, const int* in_sizes, int n_in,
                              void* d_out, int out_size, void* d_ws, size_t ws_size,
                              hipStream_t stream) {
    const float* z   = (const float*)d_in[0];   // (16,256,64,64) fp32
    const float* emb = (const float*)d_in[1];   // (1024,256) fp32
    int* out = (int*)d_out;                     // (16,64,64) int32

    ushort* eb = (ushort*)d_ws;                          // 1024*256 bf16 = 512 KB
    float*  e2 = (float*)((char*)d_ws + (size_t)NCODES * DIMS * sizeof(ushort)); // 4 KB

    prep_kernel<<<NCODES, 64, 0, stream>>>(emb, eb, e2);
    vq_kernel<<<(16 * 64 * 64) / PIXB, TPB, 0, stream>>>(z, emb, eb, e2, out);
}

// Round 3
// 212.359 us; speedup vs baseline: 1.5487x; 1.2405x over previous
//
#include <hip/hip_runtime.h>
#include <hip/hip_bf16.h>

#define TPB 256
#define NCODES 1024
#define DIMS 256
#define PIXB 64
#define XPAD 264      // xs row stride (ushorts): 528 B, 16B-aligned
#define DELTA 3.0f    // screening margin (bf16 worst-case dot error ~1.3; 3.0 is safe)
#define CAP 16        // candidate capacity per pixel (overflow -> full rescan)

typedef __attribute__((ext_vector_type(8))) short bf16x8;
typedef __attribute__((ext_vector_type(4))) float f32x4;

__device__ __forceinline__ void gll16(const void* g, void* l) {
    // async global->LDS, 16 B per lane; LDS dest = wave-uniform base + lane*16
    __builtin_amdgcn_global_load_lds(
        (const __attribute__((address_space(1))) void*)g,
        (__attribute__((address_space(3))) void*)l, 16, 0, 0);
}

// prep: eb[c][d] = bf16(emb[c][d]);  e2[c] = sum_d emb[c][d]^2 (exact fp32)
// grid 64 x 256 thr: wave w of block b handles codes b*16 + it*4 + w, it=0..3
__global__ __launch_bounds__(256) void prep_kernel(const float* __restrict__ emb,
                                                   ushort* __restrict__ eb,
                                                   float* __restrict__ e2) {
    const int w = threadIdx.x >> 6;
    const int l = threadIdx.x & 63;
#pragma unroll
    for (int it = 0; it < 4; ++it) {
        const int c = blockIdx.x * 16 + it * 4 + w;
        float4 v = *(const float4*)(emb + (size_t)c * DIMS + 4 * l);
        __hip_bfloat16 h0 = __float2bfloat16(v.x), h1 = __float2bfloat16(v.y);
        __hip_bfloat16 h2 = __float2bfloat16(v.z), h3 = __float2bfloat16(v.w);
        ushort4 u;
        u.x = *(ushort*)&h0; u.y = *(ushort*)&h1; u.z = *(ushort*)&h2; u.w = *(ushort*)&h3;
        *(ushort4*)(eb + (size_t)c * DIMS + 4 * l) = u;
        float s = v.x * v.x + v.y * v.y + v.z * v.z + v.w * v.w;
#pragma unroll
        for (int off = 1; off < 64; off <<= 1) s += __shfl_xor(s, off);
        if (l == 0) e2[c] = s;
    }
}

__global__ __launch_bounds__(TPB, 2) void vq_kernel(const float* __restrict__ z,
                                                    const float* __restrict__ emb,
                                                    const ushort* __restrict__ eb,
                                                    const float* __restrict__ e2g,
                                                    int* __restrict__ out) {
    __shared__ __align__(16) ushort xs[PIXB * XPAD];   // 33792 B: bf16 x, [px][dim]
    // es: double-buffered, WAVE-PRIVATE E tiles. dq-major: [dq][code][8 dims].
    __shared__ __align__(16) ushort es[2 * 4 * 2048];  // 32768 B
    __shared__ float wmin[4 * 64];                     // per-wave chunk min per px
    __shared__ float minval[64];                       // global running min per px
    __shared__ int   cnt[64];
    __shared__ int   cand[64 * CAP];
    __shared__ float scand[64 * CAP];                  // screened s of each candidate

    const int tid = threadIdx.x;
    const int w   = tid >> 6;     // wave 0..3
    const int L   = tid & 63;     // lane
    const int col = L & 15;       // MFMA col (= pixel within n-tile)
    const int q   = L >> 4;       // MFMA quad
    const int pixbase = blockIdx.x * PIXB;
    const int t  = pixbase >> 12;
    const int n0 = pixbase & 4095;

#define STAGE(b, cc_, kc_) do {                                                   \
        const ushort* _src = eb + ((size_t)(((cc_) << 8) + (w << 6) + L) << 8)    \
                                + ((kc_) << 5);                                   \
        ushort* _dst = &es[(((b) << 2) + w) * 2048];                              \
        gll16(_src,      _dst);                                                   \
        gll16(_src + 8,  _dst + 512);                                             \
        gll16(_src + 16, _dst + 1024);                                            \
        gll16(_src + 24, _dst + 1536);                                            \
    } while (0)

    // ---- phase 1: stage x (fp32 global -> bf16 LDS), wave w does dims w*64..+63 ----
    // z is single-use streaming data: nontemporal so it doesn't evict eb from L2.
    {
        const float* zp = z + (((size_t)t * DIMS + w * 64) << 12) + n0 + L;
#pragma unroll 8
        for (int i = 0; i < 64; ++i) {
            float v = __builtin_nontemporal_load(zp + ((size_t)i << 12));
            __hip_bfloat16 h = __float2bfloat16(v);
            xs[L * XPAD + w * 64 + i] = *(ushort*)&h;
        }
    }
    if (tid < 64) { minval[tid] = 3.4e38f; cnt[tid] = 0; }

    STAGE(0, 0, 0);        // prologue: tile for step 0 (drained by the barrier below)
    __syncthreads();       // xs ready; prologue tile landed

    // ---- phase 2: barrier-free pipelined MFMA screening, 4 chunks of 256 codes ----
#pragma unroll 1
    for (int cc = 0; cc < 4; ++cc) {
        f32x4 acc[4][4];
#pragma unroll
        for (int mt = 0; mt < 4; ++mt)
#pragma unroll
            for (int nt = 0; nt < 4; ++nt) acc[mt][nt] = (f32x4){0.f, 0.f, 0.f, 0.f};

#pragma unroll
        for (int kc = 0; kc < 8; ++kc) {
            const int s = cc * 8 + kc;
            const int b = s & 1;
            if (s < 31) {                       // issue next tile into other buffer
                const int s1 = s + 1;
                STAGE(b ^ 1, s1 >> 3, s1 & 7);
                // 8 outstanding; wait until only the 4 newest remain -> tile s ready
                asm volatile("s_waitcnt vmcnt(4)" ::: "memory");
            } else {
                asm volatile("s_waitcnt vmcnt(0)" ::: "memory");
            }

            bf16x8 af[4], bfr[4];
            const ushort* ws = &es[((b << 2) + w) * 2048 + q * 512];
#pragma unroll
            for (int mt = 0; mt < 4; ++mt)
                af[mt] = *(const bf16x8*)(ws + (mt * 16 + col) * 8);
#pragma unroll
            for (int nt = 0; nt < 4; ++nt)
                bfr[nt] = *(const bf16x8*)&xs[(nt * 16 + col) * XPAD + kc * 32 + q * 8];
#pragma unroll
            for (int mt = 0; mt < 4; ++mt)
#pragma unroll
                for (int nt = 0; nt < 4; ++nt)
                    acc[mt][nt] = __builtin_amdgcn_mfma_f32_16x16x32_bf16(
                        af[mt], bfr[nt], acc[mt][nt], 0, 0, 0);
        }

        // epilogue: s = e2[c] - 2*dot ; C layout: col=lane&15 (px), row=q*4+r (code)
        f32x4 e4[4];
#pragma unroll
        for (int mt = 0; mt < 4; ++mt)
            e4[mt] = *(const f32x4*)(e2g + cc * 256 + w * 64 + mt * 16 + q * 4);

        // 1) per-(wave,px) chunk min
#pragma unroll
        for (int nt = 0; nt < 4; ++nt) {
            float m = 3.4e38f;
#pragma unroll
            for (int mt = 0; mt < 4; ++mt)
#pragma unroll
                for (int r = 0; r < 4; ++r) {
                    float s = e4[mt][r] - 2.f * acc[mt][nt][r];
                    m = fminf(m, s);
                }
            m = fminf(m, __shfl_xor(m, 16));
            m = fminf(m, __shfl_xor(m, 32));
            wmin[w * 64 + nt * 16 + col] = m;    // all q-copies write same value
        }
        __syncthreads();
        if (tid < 64) {
            float m = minval[tid];
#pragma unroll
            for (int ww = 0; ww < 4; ++ww) m = fminf(m, wmin[ww * 64 + tid]);
            minval[tid] = m;
        }
        __syncthreads();
        // 2) candidate scan (running-min threshold => superset of final candidate set)
        //    screened s stored alongside, so phase 3 can re-filter at the FINAL min.
#pragma unroll
        for (int nt = 0; nt < 4; ++nt) {
            const int px = nt * 16 + col;
            const float thr = minval[px] + DELTA;
#pragma unroll
            for (int mt = 0; mt < 4; ++mt)
#pragma unroll
                for (int r = 0; r < 4; ++r) {
                    float s = e4[mt][r] - 2.f * acc[mt][nt][r];
                    if (s <= thr) {
                        int pos = atomicAdd(&cnt[px], 1);
                        if (pos < CAP) {
                            cand[px * CAP + pos]  = cc * 256 + w * 64 + mt * 16 + q * 4 + r;
                            scand[px * CAP + pos] = s;
                        }
                    }
                }
        }
    }
    __syncthreads();

    // ---- phase 3: final filter at the TRUE screened min, then exact rescore of
    // survivors only. wave w does px w*16..+15.
#pragma unroll 1
    for (int pi = 0; pi < 16; ++pi) {
        const int px = w * 16 + pi;
        const int n  = cnt[px];
        if (n <= CAP) {
            // tight filter: survivors = candidates within DELTA of the FINAL min.
            // The true argmin is always a survivor (bf16 error bound < DELTA).
            const float thr = minval[px] + DELTA;
            bool surv = (L < n) && (scand[px * CAP + L] <= thr);
            unsigned long long mask = __ballot(surv);
            if (__popcll(mask) == 1) {
                // singleton survivor set IS the answer: no z/emb re-read needed.
                if (L == 0) out[pixbase + px] = cand[px * CAP + (__ffsll(mask) - 1)];
                continue;
            }
            // rare (~10-15% of px): exact fp32 rescore of the survivors
            const float* zp = z + (((size_t)t * DIMS + 4 * L) << 12) + n0 + px;
            float x0 = zp[0];
            float x1 = zp[(size_t)1 << 12];
            float x2 = zp[(size_t)2 << 12];
            float x3 = zp[(size_t)3 << 12];
            float bs = 3.4e38f;
            int   bi = 0;
            unsigned long long mm = mask;
            while (mm) {
                int k = __ffsll(mm) - 1; mm &= mm - 1;
                int c = cand[px * CAP + k];
                float4 ev = *(const float4*)(emb + (size_t)c * DIMS + 4 * L);
                float p = x0 * ev.x + x1 * ev.y + x2 * ev.z + x3 * ev.w;
#pragma unroll
                for (int off = 1; off < 64; off <<= 1) p += __shfl_xor(p, off);
                float s = e2g[c] - 2.f * p;
                if (s < bs || (s == bs && c < bi)) { bs = s; bi = c; }
            }
            if (L == 0) out[pixbase + px] = bi;
        } else {
            // overflow fallback (expected never): exact scan of all codes
            const float* zp = z + (((size_t)t * DIMS + 4 * L) << 12) + n0 + px;
            float x0 = zp[0];
            float x1 = zp[(size_t)1 << 12];
            float x2 = zp[(size_t)2 << 12];
            float x3 = zp[(size_t)3 << 12];
            float bs = 3.4e38f;
            int   bi = 0;
            for (int c = 0; c < NCODES; ++c) {
                float4 ev = *(const float4*)(emb + (size_t)c * DIMS + 4 * L);
                float p = x0 * ev.x + x1 * ev.y + x2 * ev.z + x3 * ev.w;
#pragma unroll
                for (int off = 1; off < 64; off <<= 1) p += __shfl_xor(p, off);
                float s = e2g[c] - 2.f * p;
                if (s < bs || (s == bs && c < bi)) { bs = s; bi = c; }
            }
            if (L == 0) out[pixbase + px] = bi;
        }
    }
#undef STAGE
}

extern "C" void kernel_launch(void* const* d_in, const int* in_sizes, int n_in,
                              void* d_out, int out_size, void* d_ws, size_t ws_size,
                              hipStream_t stream) {
    const float* z   = (const float*)d_in[0];   // (16,256,64,64) fp32
    const float* emb = (const float*)d_in[1];   // (1024,256) fp32
    int* out = (int*)d_out;                     // (16,64,64) int32

    ushort* eb = (ushort*)d_ws;                          // 1024*256 bf16 = 512 KB
    float*  e2 = (float*)((char*)d_ws + (size_t)NCODES * DIMS * sizeof(ushort)); // 4 KB

    prep_kernel<<<64, 256, 0, stream>>>(emb, eb, e2);
    vq_kernel<<<(16 * 64 * 64) / PIXB, TPB, 0, stream>>>(z, emb, eb, e2, out);
}

// Round 4
// 198.745 us; speedup vs baseline: 1.6548x; 1.0685x over previous
//
#include <hip/hip_runtime.h>
#include <hip/hip_bf16.h>

#define TPB 256
#define NCODES 1024
#define DIMS 256
#define PIXB 64
#define DELTA 3.0f    // screening margin (bf16 worst-case dot error ~1.3; 3.0 is safe)
#define CAP 16        // candidate capacity per pixel (overflow -> full rescan)

typedef __attribute__((ext_vector_type(8))) short bf16x8;
typedef __attribute__((ext_vector_type(4))) float f32x4;

__device__ __forceinline__ void gll16(const void* g, void* l) {
    // async global->LDS, 16 B per lane; LDS dest = wave-uniform base + lane*16
    __builtin_amdgcn_global_load_lds(
        (const __attribute__((address_space(1))) void*)g,
        (__attribute__((address_space(3))) void*)l, 16, 0, 0);
}

// prep: eb[c][d] = bf16(emb[c][d]);  e2[c] = sum_d emb[c][d]^2 (exact fp32)
__global__ __launch_bounds__(256) void prep_kernel(const float* __restrict__ emb,
                                                   ushort* __restrict__ eb,
                                                   float* __restrict__ e2) {
    const int w = threadIdx.x >> 6;
    const int l = threadIdx.x & 63;
#pragma unroll
    for (int it = 0; it < 4; ++it) {
        const int c = blockIdx.x * 16 + it * 4 + w;
        float4 v = *(const float4*)(emb + (size_t)c * DIMS + 4 * l);
        __hip_bfloat16 h0 = __float2bfloat16(v.x), h1 = __float2bfloat16(v.y);
        __hip_bfloat16 h2 = __float2bfloat16(v.z), h3 = __float2bfloat16(v.w);
        ushort4 u;
        u.x = *(ushort*)&h0; u.y = *(ushort*)&h1; u.z = *(ushort*)&h2; u.w = *(ushort*)&h3;
        *(ushort4*)(eb + (size_t)c * DIMS + 4 * l) = u;
        float s = v.x * v.x + v.y * v.y + v.z * v.z + v.w * v.w;
#pragma unroll
        for (int off = 1; off < 64; off <<= 1) s += __shfl_xor(s, off);
        if (l == 0) e2[c] = s;
    }
}

__global__ __launch_bounds__(TPB, 2) void vq_kernel(const float* __restrict__ z,
                                                    const float* __restrict__ emb,
                                                    const ushort* __restrict__ eb,
                                                    const float* __restrict__ e2g,
                                                    int* __restrict__ out) {
    // xs2: bf16 x, granule-major [g=dim/8][px][8 dims] -> 16B granules, no padding.
    // bfr read: granule (kc*4+q)*64 + px  -> contiguous 16B per lane, 2-way banks.
    __shared__ __align__(16) ushort xs2[32 * 64 * 8];  // 32768 B
    // es: dual-purpose. Phase 1: two 16 KB fp32 z-scratch halves [d_local(64)][px(64)].
    // Phase 2: double-buffered wave-private E tiles [buf][wave][dq][code][8 dims].
    __shared__ __align__(16) ushort es[2 * 4 * 2048];  // 32768 B
    __shared__ float wmin[4 * 64];
    __shared__ float minval[64];
    __shared__ int   cnt[64];
    __shared__ int   cand[64 * CAP];
    __shared__ float scand[64 * CAP];                  // screened s of each candidate

    const int tid = threadIdx.x;
    const int w   = tid >> 6;     // wave 0..3
    const int L   = tid & 63;     // lane
    const int col = L & 15;       // MFMA col (= pixel within n-tile)
    const int q   = L >> 4;       // MFMA quad
    const int pixbase = blockIdx.x * PIXB;
    const int t  = pixbase >> 12;
    const int n0 = pixbase & 4095;

    // E stage: wave w stages its own 64 code rows, 32 dims of step kc, chunk cc, buf b.
#define STAGE(b, cc_, kc_) do {                                                   \
        const ushort* _src = eb + ((size_t)(((cc_) << 8) + (w << 6) + L) << 8)    \
                                + ((kc_) << 5);                                   \
        ushort* _dst = &es[(((b) << 2) + w) * 2048];                              \
        gll16(_src,      _dst);                                                   \
        gll16(_src + 8,  _dst + 512);                                             \
        gll16(_src + 16, _dst + 1024);                                            \
        gll16(_src + 24, _dst + 1536);                                            \
    } while (0)

    // ---- phase 1: DEEP-ASYNC z staging. Round r = dims r*64..+63.
    // gll16 fp32 z -> es half h as zs[d_local][px]; wave-private (wave w owns
    // d_local w*16..+15) so sync is vmcnt-only, no barriers until the end.
    const float* zbase = z + (((size_t)t * DIMS) << 12) + n0;

#define STAGE_Z(r_, h_) do {                                                      \
        _Pragma("unroll")                                                         \
        for (int i = 0; i < 4; ++i) {                                             \
            const float* _src = zbase                                             \
                + ((size_t)((r_) * 64 + w * 16 + i * 4 + (L >> 4)) << 12)         \
                + ((L & 15) << 2);                                                \
            ushort* _dst = &es[(h_) * 8192 + (w * 4 + i) * 512];                  \
            gll16(_src, _dst);                                                    \
        }                                                                         \
    } while (0)

    // convert round r from half h: zs[d_local][px] fp32 -> xs2 bf16
#define CONVERT(r_, h_) do {                                                      \
        const float* _zs = (const float*)&es[(h_) * 8192];                        \
        _Pragma("unroll")                                                         \
        for (int j = 0; j < 4; ++j) {                                             \
            const int _dl = w * 16 + j * 4;                                       \
            float _a0 = _zs[(_dl + 0) * 64 + L];                                  \
            float _a1 = _zs[(_dl + 1) * 64 + L];                                  \
            float _a2 = _zs[(_dl + 2) * 64 + L];                                  \
            float _a3 = _zs[(_dl + 3) * 64 + L];                                  \
            __hip_bfloat16 _h0 = __float2bfloat16(_a0);                           \
            __hip_bfloat16 _h1 = __float2bfloat16(_a1);                           \
            __hip_bfloat16 _h2 = __float2bfloat16(_a2);                           \
            __hip_bfloat16 _h3 = __float2bfloat16(_a3);                           \
            ushort4 _u;                                                           \
            _u.x = *(ushort*)&_h0; _u.y = *(ushort*)&_h1;                         \
            _u.z = *(ushort*)&_h2; _u.w = *(ushort*)&_h3;                         \
            const int _d0 = (r_) * 64 + _dl;                                      \
            *(ushort4*)&xs2[(size_t)(((_d0 >> 3) * 64 + L) * 8 + (_d0 & 4))] = _u;\
        }                                                                         \
    } while (0)

    STAGE_Z(0, 0);                                   // 4 loads
    STAGE_Z(1, 1);                                   // 8 outstanding
    if (tid < 64) { minval[tid] = 3.4e38f; cnt[tid] = 0; }
    asm volatile("s_waitcnt vmcnt(4)" ::: "memory"); // round 0 landed
    CONVERT(0, 0);
    asm volatile("s_waitcnt lgkmcnt(0)" ::: "memory"); // h0 reads retired
    STAGE_Z(2, 0);
    asm volatile("s_waitcnt vmcnt(4)" ::: "memory"); // round 1 landed
    CONVERT(1, 1);
    asm volatile("s_waitcnt lgkmcnt(0)" ::: "memory"); // h1 reads retired
    STAGE_Z(3, 1);
    asm volatile("s_waitcnt vmcnt(4)" ::: "memory"); // round 2 landed
    CONVERT(2, 0);
    asm volatile("s_waitcnt lgkmcnt(0)" ::: "memory"); // h0 reads retired
    STAGE(0, 0, 0);                                  // E prologue -> buf0 (=h0), overlaps r3 wait
    asm volatile("s_waitcnt vmcnt(4)" ::: "memory"); // round 3 landed (4 E-loads in flight)
    CONVERT(3, 1);
    __syncthreads();                                 // drains E prologue; xs2 visible to all

    // ---- phase 2: barrier-free pipelined MFMA screening, 4 chunks of 256 codes ----
#pragma unroll 1
    for (int cc = 0; cc < 4; ++cc) {
        f32x4 acc[4][4];
#pragma unroll
        for (int mt = 0; mt < 4; ++mt)
#pragma unroll
            for (int nt = 0; nt < 4; ++nt) acc[mt][nt] = (f32x4){0.f, 0.f, 0.f, 0.f};

#pragma unroll
        for (int kc = 0; kc < 8; ++kc) {
            const int s = cc * 8 + kc;
            const int b = s & 1;
            if (s < 31) {                       // issue next tile into other buffer
                const int s1 = s + 1;
                STAGE(b ^ 1, s1 >> 3, s1 & 7);
                // 8 outstanding; wait until only the 4 newest remain -> tile s ready
                asm volatile("s_waitcnt vmcnt(4)" ::: "memory");
            } else {
                asm volatile("s_waitcnt vmcnt(0)" ::: "memory");
            }

            bf16x8 af[4], bfr[4];
            const ushort* ws = &es[((b << 2) + w) * 2048 + q * 512];
#pragma unroll
            for (int mt = 0; mt < 4; ++mt)
                af[mt] = *(const bf16x8*)(ws + (mt * 16 + col) * 8);
#pragma unroll
            for (int nt = 0; nt < 4; ++nt)
                bfr[nt] = *(const bf16x8*)&xs2[(size_t)(((kc * 4 + q) * 64 + nt * 16 + col) * 8)];
            __builtin_amdgcn_s_setprio(1);
#pragma unroll
            for (int mt = 0; mt < 4; ++mt)
#pragma unroll
                for (int nt = 0; nt < 4; ++nt)
                    acc[mt][nt] = __builtin_amdgcn_mfma_f32_16x16x32_bf16(
                        af[mt], bfr[nt], acc[mt][nt], 0, 0, 0);
            __builtin_amdgcn_s_setprio(0);
        }

        // epilogue: s = e2[c] - 2*dot ; C layout: col=lane&15 (px), row=q*4+r (code)
        f32x4 e4[4];
#pragma unroll
        for (int mt = 0; mt < 4; ++mt)
            e4[mt] = *(const f32x4*)(e2g + cc * 256 + w * 64 + mt * 16 + q * 4);

        // 1) per-(wave,px) chunk min
#pragma unroll
        for (int nt = 0; nt < 4; ++nt) {
            float m = 3.4e38f;
#pragma unroll
            for (int mt = 0; mt < 4; ++mt)
#pragma unroll
                for (int r = 0; r < 4; ++r) {
                    float s = e4[mt][r] - 2.f * acc[mt][nt][r];
                    m = fminf(m, s);
                }
            m = fminf(m, __shfl_xor(m, 16));
            m = fminf(m, __shfl_xor(m, 32));
            wmin[w * 64 + nt * 16 + col] = m;    // all q-copies write same value
        }
        __syncthreads();
        if (tid < 64) {
            float m = minval[tid];
#pragma unroll
            for (int ww = 0; ww < 4; ++ww) m = fminf(m, wmin[ww * 64 + tid]);
            minval[tid] = m;
        }
        __syncthreads();
        // 2) candidate scan (running-min threshold => superset of final candidate set)
#pragma unroll
        for (int nt = 0; nt < 4; ++nt) {
            const int px = nt * 16 + col;
            const float thr = minval[px] + DELTA;
#pragma unroll
            for (int mt = 0; mt < 4; ++mt)
#pragma unroll
                for (int r = 0; r < 4; ++r) {
                    float s = e4[mt][r] - 2.f * acc[mt][nt][r];
                    if (s <= thr) {
                        int pos = atomicAdd(&cnt[px], 1);
                        if (pos < CAP) {
                            cand[px * CAP + pos]  = cc * 256 + w * 64 + mt * 16 + q * 4 + r;
                            scand[px * CAP + pos] = s;
                        }
                    }
                }
        }
    }
    __syncthreads();

    // ---- phase 3: final filter at the TRUE screened min, then exact rescore of
    // survivors only. wave w does px w*16..+15.
#pragma unroll 1
    for (int pi = 0; pi < 16; ++pi) {
        const int px = w * 16 + pi;
        const int n  = cnt[px];
        if (n <= CAP) {
            // tight filter: survivors = candidates within DELTA of the FINAL min.
            // The true argmin is always a survivor (bf16 error bound < DELTA).
            const float thr = minval[px] + DELTA;
            bool surv = (L < n) && (scand[px * CAP + L] <= thr);
            unsigned long long mask = __ballot(surv);
            if (__popcll(mask) == 1) {
                // singleton survivor set IS the answer: no z/emb re-read needed.
                if (L == 0) out[pixbase + px] = cand[px * CAP + (__ffsll(mask) - 1)];
                continue;
            }
            // rare: exact fp32 rescore of the survivors
            const float* zp = z + (((size_t)t * DIMS + 4 * L) << 12) + n0 + px;
            float x0 = zp[0];
            float x1 = zp[(size_t)1 << 12];
            float x2 = zp[(size_t)2 << 12];
            float x3 = zp[(size_t)3 << 12];
            float bs = 3.4e38f;
            int   bi = 0;
            unsigned long long mm = mask;
            while (mm) {
                int k = __ffsll(mm) - 1; mm &= mm - 1;
                int c = cand[px * CAP + k];
                float4 ev = *(const float4*)(emb + (size_t)c * DIMS + 4 * L);
                float p = x0 * ev.x + x1 * ev.y + x2 * ev.z + x3 * ev.w;
#pragma unroll
                for (int off = 1; off < 64; off <<= 1) p += __shfl_xor(p, off);
                float s = e2g[c] - 2.f * p;
                if (s < bs || (s == bs && c < bi)) { bs = s; bi = c; }
            }
            if (L == 0) out[pixbase + px] = bi;
        } else {
            // overflow fallback (expected never): exact scan of all codes
            const float* zp = z + (((size_t)t * DIMS + 4 * L) << 12) + n0 + px;
            float x0 = zp[0];
            float x1 = zp[(size_t)1 << 12];
            float x2 = zp[(size_t)2 << 12];
            float x3 = zp[(size_t)3 << 12];
            float bs = 3.4e38f;
            int   bi = 0;
            for (int c = 0; c < NCODES; ++c) {
                float4 ev = *(const float4*)(emb + (size_t)c * DIMS + 4 * L);
                float p = x0 * ev.x + x1 * ev.y + x2 * ev.z + x3 * ev.w;
#pragma unroll
                for (int off = 1; off < 64; off <<= 1) p += __shfl_xor(p, off);
                float s = e2g[c] - 2.f * p;
                if (s < bs || (s == bs && c < bi)) { bs = s; bi = c; }
            }
            if (L == 0) out[pixbase + px] = bi;
        }
    }
#undef STAGE
#undef STAGE_Z
#undef CONVERT
}

extern "C" void kernel_launch(void* const* d_in, const int* in_sizes, int n_in,
                              void* d_out, int out_size, void* d_ws, size_t ws_size,
                              hipStream_t stream) {
    const float* z   = (const float*)d_in[0];   // (16,256,64,64) fp32
    const float* emb = (const float*)d_in[1];   // (1024,256) fp32
    int* out = (int*)d_out;                     // (16,64,64) int32

    ushort* eb = (ushort*)d_ws;                          // 1024*256 bf16 = 512 KB
    float*  e2 = (float*)((char*)d_ws + (size_t)NCODES * DIMS * sizeof(ushort)); // 4 KB

    prep_kernel<<<64, 256, 0, stream>>>(emb, eb, e2);
    vq_kernel<<<(16 * 64 * 64) / PIXB, TPB, 0, stream>>>(z, emb, eb, e2, out);
}

// Round 6
// 172.413 us; speedup vs baseline: 1.9075x; 1.1527x over previous
//
#include <hip/hip_runtime.h>
#include <hip/hip_bf16.h>

#define TPB 256
#define NCODES 1024
#define DIMS 256
#define PIXB 64
#define DELTA 3.0f    // screening margin (bf16 worst-case dot error ~1.3; 3.0 is safe)
#define CAP 16        // candidate capacity per pixel (overflow -> full rescan)

typedef __attribute__((ext_vector_type(8))) short bf16x8;
typedef __attribute__((ext_vector_type(4))) float f32x4;

__device__ __forceinline__ void gll16(const void* g, void* l) {
    // async global->LDS, 16 B per lane; LDS dest = wave-uniform base + lane*16
    __builtin_amdgcn_global_load_lds(
        (const __attribute__((address_space(1))) void*)g,
        (__attribute__((address_space(3))) void*)l, 16, 0, 0);
}

// prep: eb_t = bf16(emb) PRE-TILED in K-loop consumption order:
//   granule(s, wv, j) = contiguous 512 ushorts (1 KB): [code cl=0..63][8 dims],
//   where s=0..31 (cc*8+kc), wv = code>>6 within chunk, j = dim-octet within 32-slice.
//   offset(c,d) = (((s*4+wv)*4 + j) << 9) + (c&63)*8 + (d&7)
// e2[c] = sum_d emb[c][d]^2 (exact fp32)
__global__ __launch_bounds__(256) void prep_kernel(const float* __restrict__ emb,
                                                   ushort* __restrict__ eb,
                                                   float* __restrict__ e2) {
    const int w = threadIdx.x >> 6;
    const int l = threadIdx.x & 63;
#pragma unroll
    for (int it = 0; it < 4; ++it) {
        const int c = blockIdx.x * 16 + it * 4 + w;
        float4 v = *(const float4*)(emb + (size_t)c * DIMS + 4 * l);  // dims 4l..4l+3
        __hip_bfloat16 h0 = __float2bfloat16(v.x), h1 = __float2bfloat16(v.y);
        __hip_bfloat16 h2 = __float2bfloat16(v.z), h3 = __float2bfloat16(v.w);
        ushort4 u;
        u.x = *(ushort*)&h0; u.y = *(ushort*)&h1; u.z = *(ushort*)&h2; u.w = *(ushort*)&h3;
        const int s  = (c >> 8) * 8 + (l >> 3);     // chunk*8 + kc  (kc = (4l)>>5)
        const int wv = (c >> 6) & 3;
        const int cl = c & 63;
        const int j  = (l >> 1) & 3;                // ((4l)&31)>>3
        const int e  = (4 * l) & 7;                 // 0 or 4
        *(ushort4*)(eb + ((((size_t)(s * 4 + wv) * 4 + j) << 9) + cl * 8 + e)) = u;
        float sq = v.x * v.x + v.y * v.y + v.z * v.z + v.w * v.w;
#pragma unroll
        for (int off = 1; off < 64; off <<= 1) sq += __shfl_xor(sq, off);
        if (l == 0) e2[c] = sq;
    }
}

__global__ __launch_bounds__(TPB, 2) void vq_kernel(const float* __restrict__ z,
                                                    const float* __restrict__ emb,
                                                    const ushort* __restrict__ eb,
                                                    const float* __restrict__ e2g,
                                                    int* __restrict__ out) {
    // xs2: bf16 x, granule-major [g=dim/8][px][8 dims] -> 16B granules, no padding.
    __shared__ __align__(16) ushort xs2[32 * 64 * 8];  // 32768 B
    // es: dual-purpose. Phase 1: two 16 KB fp32 z-scratch halves [d_local(64)][px(64)].
    // Phase 2: double-buffered wave-private E tiles [buf][wave][j][code][8 dims].
    __shared__ __align__(16) ushort es[2 * 4 * 2048];  // 32768 B
    __shared__ float wmin[4 * 64];
    __shared__ float minval[64];
    __shared__ int   cnt[64];
    __shared__ int   cand[64 * CAP];
    __shared__ float scand[64 * CAP];                  // screened s of each candidate

    const int tid = threadIdx.x;
    const int w   = tid >> 6;     // wave 0..3
    const int L   = tid & 63;     // lane
    const int col = L & 15;       // MFMA col (= pixel within n-tile)
    const int q   = L >> 4;       // MFMA quad
    const int pixbase = blockIdx.x * PIXB;
    const int t  = pixbase >> 12;
    const int n0 = pixbase & 4095;

    // E stage, step st=0..31: tile (st, w) is CONTIGUOUS 4 KB in eb_t; each gll16
    // reads a contiguous 1 KB (lane L at +L*16B) -> 16 cache lines, fully coalesced.
#define STAGE(b, st) do {                                                         \
        const ushort* _src = eb + (((size_t)(st) * 4 + w) << 11) + (L << 3);      \
        ushort* _dst = &es[(((b) << 2) + w) * 2048];                              \
        gll16(_src,        _dst);                                                 \
        gll16(_src + 512,  _dst + 512);                                           \
        gll16(_src + 1024, _dst + 1024);                                          \
        gll16(_src + 1536, _dst + 1536);                                          \
    } while (0)

    // ---- phase 1: DEEP-ASYNC z staging. Round r = dims r*64..+63.
    const float* zbase = z + (((size_t)t * DIMS) << 12) + n0;

#define STAGE_Z(r_, h_) do {                                                      \
        _Pragma("unroll")                                                         \
        for (int i = 0; i < 4; ++i) {                                             \
            const float* _src = zbase                                             \
                + ((size_t)((r_) * 64 + w * 16 + i * 4 + (L >> 4)) << 12)         \
                + ((L & 15) << 2);                                                \
            ushort* _dst = &es[(h_) * 8192 + (w * 4 + i) * 512];                  \
            gll16(_src, _dst);                                                    \
        }                                                                         \
    } while (0)

    // convert round r from half h: zs[d_local][px] fp32 -> xs2 bf16
#define CONVERT(r_, h_) do {                                                      \
        const float* _zs = (const float*)&es[(h_) * 8192];                        \
        _Pragma("unroll")                                                         \
        for (int j = 0; j < 4; ++j) {                                             \
            const int _dl = w * 16 + j * 4;                                       \
            float _a0 = _zs[(_dl + 0) * 64 + L];                                  \
            float _a1 = _zs[(_dl + 1) * 64 + L];                                  \
            float _a2 = _zs[(_dl + 2) * 64 + L];                                  \
            float _a3 = _zs[(_dl + 3) * 64 + L];                                  \
            __hip_bfloat16 _h0 = __float2bfloat16(_a0);                           \
            __hip_bfloat16 _h1 = __float2bfloat16(_a1);                           \
            __hip_bfloat16 _h2 = __float2bfloat16(_a2);                           \
            __hip_bfloat16 _h3 = __float2bfloat16(_a3);                           \
            ushort4 _u;                                                           \
            _u.x = *(ushort*)&_h0; _u.y = *(ushort*)&_h1;                         \
            _u.z = *(ushort*)&_h2; _u.w = *(ushort*)&_h3;                         \
            const int _d0 = (r_) * 64 + _dl;                                      \
            *(ushort4*)&xs2[(size_t)(((_d0 >> 3) * 64 + L) * 8 + (_d0 & 4))] = _u;\
        }                                                                         \
    } while (0)

    STAGE_Z(0, 0);                                   // 4 loads
    STAGE_Z(1, 1);                                   // 8 outstanding
    if (tid < 64) { minval[tid] = 3.4e38f; cnt[tid] = 0; }
    asm volatile("s_waitcnt vmcnt(4)" ::: "memory"); // round 0 landed
    CONVERT(0, 0);
    asm volatile("s_waitcnt lgkmcnt(0)" ::: "memory"); // h0 reads retired
    STAGE_Z(2, 0);
    asm volatile("s_waitcnt vmcnt(4)" ::: "memory"); // round 1 landed
    CONVERT(1, 1);
    asm volatile("s_waitcnt lgkmcnt(0)" ::: "memory"); // h1 reads retired
    STAGE_Z(3, 1);
    asm volatile("s_waitcnt vmcnt(4)" ::: "memory"); // round 2 landed
    CONVERT(2, 0);
    asm volatile("s_waitcnt lgkmcnt(0)" ::: "memory"); // h0 reads retired
    STAGE(0, 0);                                     // E prologue -> buf0, overlaps r3 wait
    asm volatile("s_waitcnt vmcnt(4)" ::: "memory"); // round 3 landed (4 E-loads in flight)
    CONVERT(3, 1);
    __syncthreads();                                 // drains E prologue; xs2 visible to all

    // ---- phase 2: barrier-free pipelined MFMA screening, 4 chunks of 256 codes ----
#pragma unroll 1
    for (int cc = 0; cc < 4; ++cc) {
        f32x4 acc[4][4];
#pragma unroll
        for (int mt = 0; mt < 4; ++mt)
#pragma unroll
            for (int nt = 0; nt < 4; ++nt) acc[mt][nt] = (f32x4){0.f, 0.f, 0.f, 0.f};

#pragma unroll
        for (int kc = 0; kc < 8; ++kc) {
            const int s = cc * 8 + kc;
            const int b = s & 1;
            if (s < 31) {                       // issue next tile into other buffer
                STAGE(b ^ 1, s + 1);
                // 8 outstanding; wait until only the 4 newest remain -> tile s ready
                asm volatile("s_waitcnt vmcnt(4)" ::: "memory");
            } else {
                asm volatile("s_waitcnt vmcnt(0)" ::: "memory");
            }

            bf16x8 af[4], bfr[4];
            const ushort* ws = &es[((b << 2) + w) * 2048 + q * 512];
#pragma unroll
            for (int mt = 0; mt < 4; ++mt)
                af[mt] = *(const bf16x8*)(ws + (mt * 16 + col) * 8);
#pragma unroll
            for (int nt = 0; nt < 4; ++nt)
                bfr[nt] = *(const bf16x8*)&xs2[(size_t)(((kc * 4 + q) * 64 + nt * 16 + col) * 8)];
            __builtin_amdgcn_s_setprio(1);
#pragma unroll
            for (int mt = 0; mt < 4; ++mt)
#pragma unroll
                for (int nt = 0; nt < 4; ++nt)
                    acc[mt][nt] = __builtin_amdgcn_mfma_f32_16x16x32_bf16(
                        af[mt], bfr[nt], acc[mt][nt], 0, 0, 0);
            __builtin_amdgcn_s_setprio(0);
        }

        // epilogue: s = e2[c] - 2*dot ; C layout: col=lane&15 (px), row=q*4+r (code)
        f32x4 e4[4];
#pragma unroll
        for (int mt = 0; mt < 4; ++mt)
            e4[mt] = *(const f32x4*)(e2g + cc * 256 + w * 64 + mt * 16 + q * 4);

        // 1) per-(wave,px) chunk min
#pragma unroll
        for (int nt = 0; nt < 4; ++nt) {
            float m = 3.4e38f;
#pragma unroll
            for (int mt = 0; mt < 4; ++mt)
#pragma unroll
                for (int r = 0; r < 4; ++r) {
                    float s = e4[mt][r] - 2.f * acc[mt][nt][r];
                    m = fminf(m, s);
                }
            m = fminf(m, __shfl_xor(m, 16));
            m = fminf(m, __shfl_xor(m, 32));
            wmin[w * 64 + nt * 16 + col] = m;    // all q-copies write same value
        }
        __syncthreads();
        if (tid < 64) {
            float m = minval[tid];
#pragma unroll
            for (int ww = 0; ww < 4; ++ww) m = fminf(m, wmin[ww * 64 + tid]);
            minval[tid] = m;
        }
        __syncthreads();
        // 2) candidate scan (running-min threshold => superset of final candidate set)
#pragma unroll
        for (int nt = 0; nt < 4; ++nt) {
            const int px = nt * 16 + col;
            const float thr = minval[px] + DELTA;
#pragma unroll
            for (int mt = 0; mt < 4; ++mt)
#pragma unroll
                for (int r = 0; r < 4; ++r) {
                    float s = e4[mt][r] - 2.f * acc[mt][nt][r];
                    if (s <= thr) {
                        int pos = atomicAdd(&cnt[px], 1);
                        if (pos < CAP) {
                            cand[px * CAP + pos]  = cc * 256 + w * 64 + mt * 16 + q * 4 + r;
                            scand[px * CAP + pos] = s;
                        }
                    }
                }
        }
    }
    __syncthreads();

    // ---- phase 3: final filter at the TRUE screened min, then exact rescore of
    // survivors only. wave w does px w*16..+15.
#pragma unroll 1
    for (int pi = 0; pi < 16; ++pi) {
        const int px = w * 16 + pi;
        const int n  = cnt[px];
        if (n <= CAP) {
            // tight filter: survivors = candidates within DELTA of the FINAL min.
            // The true argmin is always a survivor (bf16 error bound < DELTA).
            const float thr = minval[px] + DELTA;
            bool surv = (L < n) && (scand[px * CAP + L] <= thr);
            unsigned long long mask = __ballot(surv);
            if (__popcll(mask) == 1) {
                // singleton survivor set IS the answer: no z/emb re-read needed.
                if (L == 0) out[pixbase + px] = cand[px * CAP + (__ffsll(mask) - 1)];
                continue;
            }
            // rare: exact fp32 rescore of the survivors
            const float* zp = z + (((size_t)t * DIMS + 4 * L) << 12) + n0 + px;
            float x0 = zp[0];
            float x1 = zp[(size_t)1 << 12];
            float x2 = zp[(size_t)2 << 12];
            float x3 = zp[(size_t)3 << 12];
            float bs = 3.4e38f;
            int   bi = 0;
            unsigned long long mm = mask;
            while (mm) {
                int k = __ffsll(mm) - 1; mm &= mm - 1;
                int c = cand[px * CAP + k];
                float4 ev = *(const float4*)(emb + (size_t)c * DIMS + 4 * L);
                float p = x0 * ev.x + x1 * ev.y + x2 * ev.z + x3 * ev.w;
#pragma unroll
                for (int off = 1; off < 64; off <<= 1) p += __shfl_xor(p, off);
                float s = e2g[c] - 2.f * p;
                if (s < bs || (s == bs && c < bi)) { bs = s; bi = c; }
            }
            if (L == 0) out[pixbase + px] = bi;
        } else {
            // overflow fallback (expected never): exact scan of all codes
            const float* zp = z + (((size_t)t * DIMS + 4 * L) << 12) + n0 + px;
            float x0 = zp[0];
            float x1 = zp[(size_t)1 << 12];
            float x2 = zp[(size_t)2 << 12];
            float x3 = zp[(size_t)3 << 12];
            float bs = 3.4e38f;
            int   bi = 0;
            for (int c = 0; c < NCODES; ++c) {
                float4 ev = *(const float4*)(emb + (size_t)c * DIMS + 4 * L);
                float p = x0 * ev.x + x1 * ev.y + x2 * ev.z + x3 * ev.w;
#pragma unroll
                for (int off = 1; off < 64; off <<= 1) p += __shfl_xor(p, off);
                float s = e2g[c] - 2.f * p;
                if (s < bs || (s == bs && c < bi)) { bs = s; bi = c; }
            }
            if (L == 0) out[pixbase + px] = bi;
        }
    }
#undef STAGE
#undef STAGE_Z
#undef CONVERT
}

extern "C" void kernel_launch(void* const* d_in, const int* in_sizes, int n_in,
                              void* d_out, int out_size, void* d_ws, size_t ws_size,
                              hipStream_t stream) {
    const float* z   = (const float*)d_in[0];   // (16,256,64,64) fp32
    const float* emb = (const float*)d_in[1];   // (1024,256) fp32
    int* out = (int*)d_out;                     // (16,64,64) int32

    ushort* eb = (ushort*)d_ws;                          // tiled bf16 codebook, 512 KB
    float*  e2 = (float*)((char*)d_ws + (size_t)NCODES * DIMS * sizeof(ushort)); // 4 KB

    prep_kernel<<<64, 256, 0, stream>>>(emb, eb, e2);
    vq_kernel<<<(16 * 64 * 64) / PIXB, TPB, 0, stream>>>(z, emb, eb, e2, out);
}

// Round 7
// 163.292 us; speedup vs baseline: 2.0141x; 1.0559x over previous
//
#include <hip/hip_runtime.h>
#include <hip/hip_bf16.h>

#define TPB 512
#define NCODES 1024
#define DIMS 256
#define PIXB 64
#define DELTA 3.0f    // screening margin (bf16 worst-case dot error ~1.3; 3.0 is safe)
#define CAP 16        // candidate capacity per pixel (overflow -> full rescan)

typedef __attribute__((ext_vector_type(8))) short bf16x8;
typedef __attribute__((ext_vector_type(4))) float f32x4;

__device__ __forceinline__ void gll16(const void* g, void* l) {
    // async global->LDS, 16 B per lane; LDS dest = wave-uniform base + lane*16
    __builtin_amdgcn_global_load_lds(
        (const __attribute__((address_space(1))) void*)g,
        (__attribute__((address_space(3))) void*)l, 16, 0, 0);
}

// prep: eb_t = bf16(emb) PRE-TILED in 8-wave K-loop consumption order:
//   tile(st, w8) = contiguous 1024 ushorts (2 KB): [j(0..3)][code cl(0..31)][8 dims]
//   st = (c>>8)*8 + (d>>5)  (chunk*8 + kc),  w8 = (c>>5)&7,  cl = c&31,
//   j = (d>>3)&3, e = d&7.
//   offset(c,d) = ((st*8 + w8) << 10) + (j << 8) + cl*8 + e
// e2[c] = sum_d emb[c][d]^2 (exact fp32)
__global__ __launch_bounds__(256) void prep_kernel(const float* __restrict__ emb,
                                                   ushort* __restrict__ eb,
                                                   float* __restrict__ e2) {
    const int w = threadIdx.x >> 6;
    const int l = threadIdx.x & 63;
    const int c = blockIdx.x * 4 + w;
    float4 v = *(const float4*)(emb + (size_t)c * DIMS + 4 * l);  // dims 4l..4l+3
    __hip_bfloat16 h0 = __float2bfloat16(v.x), h1 = __float2bfloat16(v.y);
    __hip_bfloat16 h2 = __float2bfloat16(v.z), h3 = __float2bfloat16(v.w);
    ushort4 u;
    u.x = *(ushort*)&h0; u.y = *(ushort*)&h1; u.z = *(ushort*)&h2; u.w = *(ushort*)&h3;
    const int st = (c >> 8) * 8 + (l >> 3);
    const int w8 = (c >> 5) & 7;
    const int cl = c & 31;
    const int j  = (l >> 1) & 3;
    const int e  = (4 * l) & 7;                 // 0 or 4
    *(ushort4*)(eb + (((size_t)(st * 8 + w8) << 10) + (j << 8) + cl * 8 + e)) = u;
    float sq = v.x * v.x + v.y * v.y + v.z * v.z + v.w * v.w;
#pragma unroll
    for (int off = 1; off < 64; off <<= 1) sq += __shfl_xor(sq, off);
    if (l == 0) e2[c] = sq;
}

__global__ __launch_bounds__(TPB, 4) void vq_kernel(const float* __restrict__ z,
                                                    const float* __restrict__ emb,
                                                    const ushort* __restrict__ eb,
                                                    const float* __restrict__ e2g,
                                                    int* __restrict__ out) {
    // xs2: bf16 x, granule-major [g=dim/8][px][8 dims] -> 16B granules, no padding.
    __shared__ __align__(16) ushort xs2[32 * 64 * 8];  // 32768 B
    // es: dual-purpose. Phase 1: two 16 KB fp32 z-scratch halves [d_local(64)][px(64)].
    // Phase 2: double-buffered WAVE-PRIVATE E tiles [buf][wave(8)][j][code(32)][8].
    __shared__ __align__(16) ushort es[2 * 8 * 1024];  // 32768 B
    __shared__ float wmin[8 * 64];                     // per-wave chunk min per px
    __shared__ float minval[64];
    __shared__ int   cnt[64];
    __shared__ int   cand[64 * CAP];
    __shared__ float scand[64 * CAP];                  // screened s of each candidate

    const int tid = threadIdx.x;
    const int w   = tid >> 6;     // wave 0..7 (owns 32 codes per chunk)
    const int L   = tid & 63;     // lane
    const int col = L & 15;       // MFMA col (= pixel within n-tile)
    const int q   = L >> 4;       // MFMA quad
    const int pixbase = blockIdx.x * PIXB;
    const int t  = pixbase >> 12;
    const int n0 = pixbase & 4095;

    // E stage, step st: tile (st, w) is CONTIGUOUS 2 KB in eb_t; 2 gll16, each a
    // contiguous 1 KB (lane L at +L*16B) -> fully coalesced. Wave-private: vmcnt sync.
#define STAGE(b, st) do {                                                         \
        const ushort* _src = eb + (((size_t)(st) * 8 + w) << 10) + (L << 3);      \
        ushort* _dst = &es[(((b) << 3) + w) * 1024];                              \
        gll16(_src,       _dst);                                                  \
        gll16(_src + 512, _dst + 512);                                            \
    } while (0)

    // ---- phase 1: DEEP-ASYNC z staging. Round r = dims r*64..+63.
    const float* zbase = z + (((size_t)t * DIMS) << 12) + n0;

#define STAGE_Z(r_, h_) do {                                                      \
        _Pragma("unroll")                                                         \
        for (int i = 0; i < 2; ++i) {                                             \
            const float* _src = zbase                                             \
                + ((size_t)((r_) * 64 + w * 8 + i * 4 + (L >> 4)) << 12)          \
                + ((L & 15) << 2);                                                \
            ushort* _dst = &es[(h_) * 8192 + (w * 2 + i) * 512];                  \
            gll16(_src, _dst);                                                    \
        }                                                                         \
    } while (0)

    // convert round r from half h: zs[d_local][px] fp32 -> xs2 bf16; wave w owns
    // d_local w*8..+7 (both the staging above and the reads here -> wave-private).
#define CONVERT(r_, h_) do {                                                      \
        const float* _zs = (const float*)&es[(h_) * 8192];                        \
        _Pragma("unroll")                                                         \
        for (int j = 0; j < 2; ++j) {                                             \
            const int _dl = w * 8 + j * 4;                                        \
            float _a0 = _zs[(_dl + 0) * 64 + L];                                  \
            float _a1 = _zs[(_dl + 1) * 64 + L];                                  \
            float _a2 = _zs[(_dl + 2) * 64 + L];                                  \
            float _a3 = _zs[(_dl + 3) * 64 + L];                                  \
            __hip_bfloat16 _h0 = __float2bfloat16(_a0);                           \
            __hip_bfloat16 _h1 = __float2bfloat16(_a1);                           \
            __hip_bfloat16 _h2 = __float2bfloat16(_a2);                           \
            __hip_bfloat16 _h3 = __float2bfloat16(_a3);                           \
            ushort4 _u;                                                           \
            _u.x = *(ushort*)&_h0; _u.y = *(ushort*)&_h1;                         \
            _u.z = *(ushort*)&_h2; _u.w = *(ushort*)&_h3;                         \
            const int _d0 = (r_) * 64 + _dl;                                      \
            *(ushort4*)&xs2[(size_t)(((_d0 >> 3) * 64 + L) * 8 + (_d0 & 4))] = _u;\
        }                                                                         \
    } while (0)

    STAGE_Z(0, 0);                                   // 2 loads
    STAGE_Z(1, 1);                                   // 4 outstanding
    if (tid < 64) { minval[tid] = 3.4e38f; cnt[tid] = 0; }
    asm volatile("s_waitcnt vmcnt(2)" ::: "memory"); // round 0 landed
    CONVERT(0, 0);
    asm volatile("s_waitcnt lgkmcnt(0)" ::: "memory"); // h0 reads retired
    STAGE_Z(2, 0);
    asm volatile("s_waitcnt vmcnt(2)" ::: "memory"); // round 1 landed
    CONVERT(1, 1);
    asm volatile("s_waitcnt lgkmcnt(0)" ::: "memory"); // h1 reads retired
    STAGE_Z(3, 1);
    asm volatile("s_waitcnt vmcnt(2)" ::: "memory"); // round 2 landed
    CONVERT(2, 0);
    asm volatile("s_waitcnt lgkmcnt(0)" ::: "memory"); // h0 reads retired
    STAGE(0, 0);                                     // E prologue -> buf0, overlaps r3 wait
    asm volatile("s_waitcnt vmcnt(2)" ::: "memory"); // round 3 landed (2 E-loads in flight)
    CONVERT(3, 1);
    __syncthreads();                                 // xs2 visible to all waves

    // ---- phase 2: barrier-free pipelined MFMA screening, 4 chunks of 256 codes.
    // Wave w owns codes w*32..+31 of each chunk: acc 2 mt x 4 nt.
#pragma unroll 1
    for (int cc = 0; cc < 4; ++cc) {
        f32x4 acc[2][4];
#pragma unroll
        for (int mt = 0; mt < 2; ++mt)
#pragma unroll
            for (int nt = 0; nt < 4; ++nt) acc[mt][nt] = (f32x4){0.f, 0.f, 0.f, 0.f};

#pragma unroll
        for (int kc = 0; kc < 8; ++kc) {
            const int s = cc * 8 + kc;
            const int b = s & 1;
            if (s < 31) {                       // issue next tile into other buffer
                STAGE(b ^ 1, s + 1);
                // 4 outstanding; wait until only the 2 newest remain -> tile s ready
                asm volatile("s_waitcnt vmcnt(2)" ::: "memory");
            } else {
                asm volatile("s_waitcnt vmcnt(0)" ::: "memory");
            }

            bf16x8 af[2], bfr[4];
            const ushort* ws = &es[((b << 3) + w) * 1024 + (q << 8)];
#pragma unroll
            for (int mt = 0; mt < 2; ++mt)
                af[mt] = *(const bf16x8*)(ws + (mt * 16 + col) * 8);
#pragma unroll
            for (int nt = 0; nt < 4; ++nt)
                bfr[nt] = *(const bf16x8*)&xs2[(size_t)(((kc * 4 + q) * 64 + nt * 16 + col) * 8)];
            __builtin_amdgcn_s_setprio(1);
#pragma unroll
            for (int mt = 0; mt < 2; ++mt)
#pragma unroll
                for (int nt = 0; nt < 4; ++nt)
                    acc[mt][nt] = __builtin_amdgcn_mfma_f32_16x16x32_bf16(
                        af[mt], bfr[nt], acc[mt][nt], 0, 0, 0);
            __builtin_amdgcn_s_setprio(0);
        }

        // epilogue: s = e2[c] - 2*dot ; C layout: col=lane&15 (px), row=q*4+r (code)
        f32x4 e4[2];
#pragma unroll
        for (int mt = 0; mt < 2; ++mt)
            e4[mt] = *(const f32x4*)(e2g + cc * 256 + w * 32 + mt * 16 + q * 4);

        // 1) per-(wave,px) chunk min
#pragma unroll
        for (int nt = 0; nt < 4; ++nt) {
            float m = 3.4e38f;
#pragma unroll
            for (int mt = 0; mt < 2; ++mt)
#pragma unroll
                for (int r = 0; r < 4; ++r) {
                    float s = e4[mt][r] - 2.f * acc[mt][nt][r];
                    m = fminf(m, s);
                }
            m = fminf(m, __shfl_xor(m, 16));
            m = fminf(m, __shfl_xor(m, 32));
            wmin[w * 64 + nt * 16 + col] = m;    // all q-copies write same value
        }
        __syncthreads();
        if (tid < 64) {
            float m = minval[tid];
#pragma unroll
            for (int ww = 0; ww < 8; ++ww) m = fminf(m, wmin[ww * 64 + tid]);
            minval[tid] = m;
        }
        __syncthreads();
        // 2) candidate scan (running-min threshold => superset of final candidate set)
#pragma unroll
        for (int nt = 0; nt < 4; ++nt) {
            const int px = nt * 16 + col;
            const float thr = minval[px] + DELTA;
#pragma unroll
            for (int mt = 0; mt < 2; ++mt)
#pragma unroll
                for (int r = 0; r < 4; ++r) {
                    float s = e4[mt][r] - 2.f * acc[mt][nt][r];
                    if (s <= thr) {
                        int pos = atomicAdd(&cnt[px], 1);
                        if (pos < CAP) {
                            cand[px * CAP + pos]  = cc * 256 + w * 32 + mt * 16 + q * 4 + r;
                            scand[px * CAP + pos] = s;
                        }
                    }
                }
        }
    }
    __syncthreads();

    // ---- phase 3: final filter at the TRUE screened min, then exact rescore of
    // survivors only. wave w does px w*8..+7.
#pragma unroll 1
    for (int pi = 0; pi < 8; ++pi) {
        const int px = w * 8 + pi;
        const int n  = cnt[px];
        if (n <= CAP) {
            // tight filter: survivors = candidates within DELTA of the FINAL min.
            // The true argmin is always a survivor (bf16 error bound < DELTA).
            const float thr = minval[px] + DELTA;
            bool surv = (L < n) && (scand[px * CAP + L] <= thr);
            unsigned long long mask = __ballot(surv);
            if (__popcll(mask) == 1) {
                // singleton survivor set IS the answer: no z/emb re-read needed.
                if (L == 0) out[pixbase + px] = cand[px * CAP + (__ffsll(mask) - 1)];
                continue;
            }
            // rare: exact fp32 rescore of the survivors
            const float* zp = z + (((size_t)t * DIMS + 4 * L) << 12) + n0 + px;
            float x0 = zp[0];
            float x1 = zp[(size_t)1 << 12];
            float x2 = zp[(size_t)2 << 12];
            float x3 = zp[(size_t)3 << 12];
            float bs = 3.4e38f;
            int   bi = 0;
            unsigned long long mm = mask;
            while (mm) {
                int k = __ffsll(mm) - 1; mm &= mm - 1;
                int c = cand[px * CAP + k];
                float4 ev = *(const float4*)(emb + (size_t)c * DIMS + 4 * L);
                float p = x0 * ev.x + x1 * ev.y + x2 * ev.z + x3 * ev.w;
#pragma unroll
                for (int off = 1; off < 64; off <<= 1) p += __shfl_xor(p, off);
                float s = e2g[c] - 2.f * p;
                if (s < bs || (s == bs && c < bi)) { bs = s; bi = c; }
            }
            if (L == 0) out[pixbase + px] = bi;
        } else {
            // overflow fallback (expected never): exact scan of all codes
            const float* zp = z + (((size_t)t * DIMS + 4 * L) << 12) + n0 + px;
            float x0 = zp[0];
            float x1 = zp[(size_t)1 << 12];
            float x2 = zp[(size_t)2 << 12];
            float x3 = zp[(size_t)3 << 12];
            float bs = 3.4e38f;
            int   bi = 0;
            for (int c = 0; c < NCODES; ++c) {
                float4 ev = *(const float4*)(emb + (size_t)c * DIMS + 4 * L);
                float p = x0 * ev.x + x1 * ev.y + x2 * ev.z + x3 * ev.w;
#pragma unroll
                for (int off = 1; off < 64; off <<= 1) p += __shfl_xor(p, off);
                float s = e2g[c] - 2.f * p;
                if (s < bs || (s == bs && c < bi)) { bs = s; bi = c; }
            }
            if (L == 0) out[pixbase + px] = bi;
        }
    }
#undef STAGE
#undef STAGE_Z
#undef CONVERT
}

extern "C" void kernel_launch(void* const* d_in, const int* in_sizes, int n_in,
                              void* d_out, int out_size, void* d_ws, size_t ws_size,
                              hipStream_t stream) {
    const float* z   = (const float*)d_in[0];   // (16,256,64,64) fp32
    const float* emb = (const float*)d_in[1];   // (1024,256) fp32
    int* out = (int*)d_out;                     // (16,64,64) int32

    ushort* eb = (ushort*)d_ws;                          // tiled bf16 codebook, 512 KB
    float*  e2 = (float*)((char*)d_ws + (size_t)NCODES * DIMS * sizeof(ushort)); // 4 KB

    prep_kernel<<<256, 256, 0, stream>>>(emb, eb, e2);
    vq_kernel<<<(16 * 64 * 64) / PIXB, TPB, 0, stream>>>(z, emb, eb, e2, out);
}